// Round 8
// baseline (203.939 us; speedup 1.0000x reference)
//
#include <hip/hip_runtime.h>

#define BB 2
#define SS 2048
#define DD 1024
#define NH 16
#define NKVH 4
#define HD 64
#define QKVN 1536          // fused Wqkv output columns: 1024 q | 256 k | 256 v
#define SCALE 0.125f       // 64^-0.5, exact power of 2 -> folded into Q frags

typedef __bf16 bf16;
typedef __bf16 bf16x4 __attribute__((ext_vector_type(4)));
typedef __bf16 bf16x8 __attribute__((ext_vector_type(8)));
typedef float floatx4 __attribute__((ext_vector_type(4)));

#define ASYNC16(gp, lp) __builtin_amdgcn_global_load_lds(                      \
    (const __attribute__((address_space(1))) unsigned int*)(gp),               \
    (__attribute__((address_space(3))) unsigned int*)(lp), 16, 0, 0)

// ---------- prep: LDS-tiled weight transposes + hs cast ----------
__global__ __launch_bounds__(256) void prep_kernel(const float* __restrict__ hs,
                                                   const float* __restrict__ Wq,
                                                   const float* __restrict__ Wk,
                                                   const float* __restrict__ Wv,
                                                   const float* __restrict__ Wo,
                                                   bf16* __restrict__ hsb,
                                                   bf16* __restrict__ WqkvT,
                                                   bf16* __restrict__ WoT) {
    __shared__ bf16 tl[64 * 66];
    int bidx = blockIdx.x, t = threadIdx.x;
    const int NT_QKV = 16 * 24;    // K/64 x QKVN/64
    const int NT_WO  = 16 * 16;
    if (bidx < NT_QKV + NT_WO) {
        int k0, n0, stride;
        const float* src;
        bf16* dst;
        if (bidx < NT_QKV) {
            int tk = bidx / 24, tn = bidx - tk * 24;
            k0 = tk * 64; n0 = tn * 64;
            if (n0 < 1024)      { src = Wq + n0;          stride = 1024; }
            else if (n0 < 1280) { src = Wk + (n0 - 1024); stride = 256;  }
            else                { src = Wv + (n0 - 1280); stride = 256;  }
            dst = WqkvT + (size_t)n0 * DD + k0;
        } else {
            int j = bidx - NT_QKV;
            int tk = j >> 4, tn = j & 15;
            k0 = tk * 64; n0 = tn * 64;
            src = Wo + n0; stride = 1024;
            dst = WoT + (size_t)n0 * DD + k0;
        }
        int c = t & 63, r0 = (t >> 6) * 16;
        for (int j = 0; j < 16; ++j)
            tl[c * 66 + r0 + j] = (bf16)src[(size_t)(k0 + r0 + j) * stride + c];
        __syncthreads();
        for (int j = 0; j < 16; ++j)
            dst[(size_t)(r0 + j) * DD + c] = tl[(r0 + j) * 66 + c];
    } else {
        int i = (bidx - (NT_QKV + NT_WO)) * 256 + t;   // n4 = 1048576 exactly
        float4 v = ((const float4*)hs)[i];
        ((bf16x4*)hsb)[i] = bf16x4{(bf16)v.x, (bf16)v.y, (bf16)v.z, (bf16)v.w};
    }
}

// ---------- QKV GEMM (128x64 tile) with fused RoPE + scatter epilogue ----------
__global__ __launch_bounds__(256) void gemm_qkv(const bf16* __restrict__ A,
                                                const bf16* __restrict__ Bt,
                                                const float* __restrict__ cosb,
                                                const float* __restrict__ sinb,
                                                bf16* __restrict__ Qr,
                                                bf16* __restrict__ Kr,
                                                bf16* __restrict__ Vt) {
    __shared__ bf16 As[128 * 32];
    __shared__ bf16 Bs[64 * 32];
    int t = threadIdx.x;
    int wave = t >> 6, lane = t & 63;
    int lm = lane & 15, quad = lane >> 4;
    int m0 = blockIdx.x * 128, n0 = blockIdx.y * 64;
    int wr = wave >> 1, wc = wave & 1;      // 64m x 32n per wave
    const int K = DD;

    int srow = t >> 2;                      // 0..63
    int scol = (t & 3) * 8;
    const bf16* ga = A  + (size_t)(m0 + srow) * K + scol;
    const bf16* gb = Bt + (size_t)(n0 + srow) * K + scol;
    bf16* la0 = &As[wave * 512];
    bf16* lb0 = &Bs[wave * 512];

    floatx4 acc[4][2];
    for (int i = 0; i < 4; ++i)
        for (int j = 0; j < 2; ++j) acc[i][j] = floatx4{0.f, 0.f, 0.f, 0.f};

    for (int ks = 0; ks < K; ks += 32) {
        __syncthreads();
        ASYNC16(ga + ks,                la0);
        ASYNC16(ga + ks + (size_t)64*K, la0 + 2048);
        ASYNC16(gb + ks,                lb0);
        __syncthreads();
        bf16x8 af[4], bfr[2];
        for (int mi = 0; mi < 4; ++mi)
            af[mi] = *(const bf16x8*)&As[(wr * 64 + mi * 16 + lm) * 32 + quad * 8];
        for (int ni = 0; ni < 2; ++ni)
            bfr[ni] = *(const bf16x8*)&Bs[(wc * 32 + ni * 16 + lm) * 32 + quad * 8];
        for (int mi = 0; mi < 4; ++mi)
            for (int ni = 0; ni < 2; ++ni)
                acc[mi][ni] = __builtin_amdgcn_mfma_f32_16x16x32_bf16(af[mi], bfr[ni],
                                                                      acc[mi][ni], 0, 0, 0);
    }
    bool odd = lm & 1;
    for (int mi = 0; mi < 4; ++mi)
        for (int ni = 0; ni < 2; ++ni) {
            int c0 = n0 + wc * 32 + ni * 16;
            int row0 = m0 + wr * 64 + mi * 16 + quad * 4;
            floatx4 a = acc[mi][ni];
            int d = (c0 & 63) + lm;
            if (c0 < 1280) {               // Q or K: apply RoPE
                int ii = d >> 1;
                for (int r = 0; r < 4; ++r) {
                    int row = row0 + r;
                    float self = a[r];
                    float part = __shfl_xor(self, 1);
                    float cc = cosb[(size_t)row * 32 + ii];
                    float sn = sinb[(size_t)row * 32 + ii];
                    float outv = odd ? fmaf(part, sn, self * cc)
                                     : fmaf(self, cc, -part * sn);
                    int s = row & (SS - 1), b = row >> 11;
                    if (c0 < 1024) {
                        int h = c0 >> 6;
                        Qr[((size_t)(b * NH + h) * SS + s) * HD + d] = (bf16)outv;
                    } else {
                        int kvh = (c0 - 1024) >> 6;
                        Kr[((size_t)(b * NKVH + kvh) * SS + s) * HD + d] = (bf16)outv;
                    }
                }
            } else {                       // V: transposed packed store
                int kvh = (c0 - 1280) >> 6;
                bf16x4 pk = {(bf16)a[0], (bf16)a[1], (bf16)a[2], (bf16)a[3]};
                int s0 = row0 & (SS - 1), b = row0 >> 11;
                *(bf16x4*)&Vt[((size_t)(b * NKVH + kvh) * HD + d) * SS + s0] = pk;
            }
        }
}

// ---------- O-projection GEMM (128x64 tile, fp32 out) ----------
__global__ __launch_bounds__(256) void gemm_out(const bf16* __restrict__ A,
                                                const bf16* __restrict__ Bt,
                                                float* __restrict__ Cf,
                                                int M, int N, int K) {
    __shared__ bf16 As[128 * 32];
    __shared__ bf16 Bs[64 * 32];
    int t = threadIdx.x;
    int wave = t >> 6, lane = t & 63;
    int lm = lane & 15, quad = lane >> 4;
    int m0 = blockIdx.x * 128, n0 = blockIdx.y * 64;
    int wr = wave >> 1, wc = wave & 1;

    int srow = t >> 2;
    int scol = (t & 3) * 8;
    const bf16* ga = A  + (size_t)(m0 + srow) * K + scol;
    const bf16* gb = Bt + (size_t)(n0 + srow) * K + scol;
    bf16* la0 = &As[wave * 512];
    bf16* lb0 = &Bs[wave * 512];

    floatx4 acc[4][2];
    for (int i = 0; i < 4; ++i)
        for (int j = 0; j < 2; ++j) acc[i][j] = floatx4{0.f, 0.f, 0.f, 0.f};

    for (int ks = 0; ks < K; ks += 32) {
        __syncthreads();
        ASYNC16(ga + ks,                la0);
        ASYNC16(ga + ks + (size_t)64*K, la0 + 2048);
        ASYNC16(gb + ks,                lb0);
        __syncthreads();
        bf16x8 af[4], bfr[2];
        for (int mi = 0; mi < 4; ++mi)
            af[mi] = *(const bf16x8*)&As[(wr * 64 + mi * 16 + lm) * 32 + quad * 8];
        for (int ni = 0; ni < 2; ++ni)
            bfr[ni] = *(const bf16x8*)&Bs[(wc * 32 + ni * 16 + lm) * 32 + quad * 8];
        for (int mi = 0; mi < 4; ++mi)
            for (int ni = 0; ni < 2; ++ni)
                acc[mi][ni] = __builtin_amdgcn_mfma_f32_16x16x32_bf16(af[mi], bfr[ni],
                                                                      acc[mi][ni], 0, 0, 0);
    }
    for (int mi = 0; mi < 4; ++mi)
        for (int ni = 0; ni < 2; ++ni)
            for (int r = 0; r < 4; ++r) {
                size_t row = (size_t)(m0 + wr * 64 + mi * 16 + quad * 4 + r);
                Cf[row * N + n0 + wc * 32 + ni * 16 + lm] = acc[mi][ni][r];
            }
}

// ---------- flash attention: 4 waves, 32 queries/wave (2 tiles share K/V frags) ----------
// DS-pipe optimization: K frags + V frags are query-independent -> loaded once per
// wave-chunk, used by both q-tiles (2x MFMA per LDS byte vs R6). 512 WGs, j/j^1
// pairing keeps per-CU chunk sum constant (34); bid&7 XCD-pins (b,kvh).
__global__ __launch_bounds__(256) void attn_kernel(const bf16* __restrict__ Qr,
                                                   const bf16* __restrict__ Kr,
                                                   const bf16* __restrict__ Vt,
                                                   bf16* __restrict__ ctx) {
    __shared__ __align__(16) bf16 kv[2][8192];        // per buf: K [0,4096) | V [4096,8192)
    __shared__ __align__(16) bf16 p_lds[4][2][16][72];
    int t = threadIdx.x;
    int wave = t >> 6, lane = t & 63;
    int lm = lane & 15, quad = lane >> 4;

    int bid = blockIdx.x;
    int grp = bid & 7;                 // XCD group = b*4 + kvh
    int j = bid >> 3;                  // 0..63 within group
    int b = grp >> 2, kvh = grp & 3;
    int pp = j >> 1, e = j & 1;
    int h = kvh * 4 + (pp & 3);
    int base = pp >> 2;                // 0..7
    int qblk = e ? (15 - base) : base; // adjacent j (same CU) sum to 34 chunks
    int q0w = qblk * 128 + wave * 32;  // tile A: q0w..+15, tile B: q0w+16..+31
    int nch = 2 * qblk + 2;
    int lastck = (q0w + 31) >> 6;

    // Q fragments for both tiles, pre-scaled by SCALE (exact)
    const bf16* qpA = Qr + ((size_t)(b * NH + h) * SS + q0w + lm) * HD;
    bf16x8 qfA0 = *(const bf16x8*)(qpA + quad * 8);
    bf16x8 qfA1 = *(const bf16x8*)(qpA + 32 + quad * 8);
    const bf16* qpB = qpA + 16 * HD;
    bf16x8 qfB0 = *(const bf16x8*)(qpB + quad * 8);
    bf16x8 qfB1 = *(const bf16x8*)(qpB + 32 + quad * 8);
    for (int i = 0; i < 8; ++i) {
        qfA0[i] = (bf16)((float)qfA0[i] * SCALE);
        qfA1[i] = (bf16)((float)qfA1[i] * SCALE);
        qfB0[i] = (bf16)((float)qfB0[i] * SCALE);
        qfB1[i] = (bf16)((float)qfB1[i] * SCALE);
    }

    const bf16* kbase = Kr + (size_t)(b * NKVH + kvh) * SS * HD;
    const bf16* vbase = Vt + (size_t)(b * NKVH + kvh) * HD * SS;
    int srow = t >> 3;                         // 0..31
    int su   = (t & 7) ^ (srow & 7);           // XOR swizzle (async-LDS forbids pads)
    const bf16* gk = kbase + (size_t)srow * HD + su * 8;
    const bf16* gv = vbase + (size_t)srow * SS + su * 8;

#define STAGE(bufi, kb) do {                                                   \
        ASYNC16(gk + (size_t)(kb) * HD,        &kv[bufi][0]    + wave * 512);  \
        ASYNC16(gk + (size_t)((kb) + 32) * HD, &kv[bufi][2048] + wave * 512);  \
        ASYNC16(gv + (kb),                     &kv[bufi][4096] + wave * 512);  \
        ASYNC16(gv + (size_t)32 * SS + (kb),   &kv[bufi][6144] + wave * 512);  \
    } while (0)

    float mA = -1e30f, lA = 0.f, mB = -1e30f, lB = 0.f;
    floatx4 oA[4], oB[4];
    for (int dt = 0; dt < 4; ++dt) {
        oA[dt] = floatx4{0.f, 0.f, 0.f, 0.f};
        oB[dt] = floatx4{0.f, 0.f, 0.f, 0.f};
    }

    STAGE(0, 0);
    __syncthreads();                           // buf0 staged (vmcnt drained)

    int lsw = lm & 7;
    for (int ck = 0; ck < nch; ++ck) {
        int kb = ck * 64;
        if (ck + 1 < nch) STAGE((ck + 1) & 1, kb + 64);
        const bf16* kbuf = &kv[ck & 1][0];
        const bf16* vbuf = kbuf + 4096;

        if (ck <= lastck) {
            // S^T for both tiles; K frags shared
            floatx4 sA[4], sB[4];
            for (int tt = 0; tt < 4; ++tt) {
                int kk = tt * 16 + lm;             // kk&7 == lm&7
                const bf16* krow = kbuf + kk * 64;
                bf16x8 k0 = *(const bf16x8*)(krow + ((quad ^ lsw) * 8));
                bf16x8 k1 = *(const bf16x8*)(krow + (((quad + 4) ^ lsw) * 8));
                floatx4 s = {0.f, 0.f, 0.f, 0.f};
                s = __builtin_amdgcn_mfma_f32_16x16x32_bf16(k0, qfA0, s, 0, 0, 0);
                s = __builtin_amdgcn_mfma_f32_16x16x32_bf16(k1, qfA1, s, 0, 0, 0);
                sA[tt] = s;
                floatx4 s2 = {0.f, 0.f, 0.f, 0.f};
                s2 = __builtin_amdgcn_mfma_f32_16x16x32_bf16(k0, qfB0, s2, 0, 0, 0);
                s2 = __builtin_amdgcn_mfma_f32_16x16x32_bf16(k1, qfB1, s2, 0, 0, 0);
                sB[tt] = s2;
            }
            if (ck == lastck) {                    // causal mask (diag chunk only)
                for (int tt = 0; tt < 4; ++tt)
                    for (int r = 0; r < 4; ++r) {
                        int key = kb + tt * 16 + quad * 4 + r;
                        if (key > q0w + lm)      sA[tt][r] = -1e30f;
                        if (key > q0w + 16 + lm) sB[tt][r] = -1e30f;
                    }
            }
            // ---- softmax + P-pack per tile ----
            auto softmax_tile = [&](floatx4* st, float& m_prev, float& l_prev,
                                    int pbuf) -> float {
                float tm[4];
                for (int tt = 0; tt < 4; ++tt)
                    tm[tt] = fmaxf(fmaxf(st[tt][0], st[tt][1]),
                                   fmaxf(st[tt][2], st[tt][3]));
                float mx = fmaxf(fmaxf(tm[0], tm[1]), fmaxf(tm[2], tm[3]));
                mx = fmaxf(mx, __shfl_xor(mx, 16));
                mx = fmaxf(mx, __shfl_xor(mx, 32));
                float m_new = fmaxf(m_prev, mx);
                float alpha = __expf(m_prev - m_new);
                m_prev = m_new;
                float ts[4];
                for (int tt = 0; tt < 4; ++tt) {
                    float p0 = __expf(st[tt][0] - m_new);
                    float p1 = __expf(st[tt][1] - m_new);
                    float p2 = __expf(st[tt][2] - m_new);
                    float p3 = __expf(st[tt][3] - m_new);
                    st[tt] = floatx4{p0, p1, p2, p3};
                    ts[tt] = (p0 + p1) + (p2 + p3);
                }
                float ls = (ts[0] + ts[1]) + (ts[2] + ts[3]);
                ls += __shfl_xor(ls, 16);
                ls += __shfl_xor(ls, 32);
                l_prev = l_prev * alpha + ls;
                for (int tt = 0; tt < 4; ++tt) {
                    bf16x4 pk = {(bf16)st[tt][0], (bf16)st[tt][1],
                                 (bf16)st[tt][2], (bf16)st[tt][3]};
                    *(bf16x4*)&p_lds[wave][pbuf][lm][tt * 16 + quad * 4] = pk;
                }
                return alpha;
            };
            float alphaA = softmax_tile(sA, mA, lA, 0);
            float alphaB = softmax_tile(sB, mB, lB, 1);

            for (int r = 0; r < 4; ++r) {
                float aA = __shfl(alphaA, quad * 4 + r);
                float aB = __shfl(alphaB, quad * 4 + r);
                for (int dt = 0; dt < 4; ++dt) { oA[dt][r] *= aA; oB[dt][r] *= aB; }
            }
            bf16x8 paA0 = *(const bf16x8*)&p_lds[wave][0][lm][quad * 8];
            bf16x8 paA1 = *(const bf16x8*)&p_lds[wave][0][lm][32 + quad * 8];
            bf16x8 paB0 = *(const bf16x8*)&p_lds[wave][1][lm][quad * 8];
            bf16x8 paB1 = *(const bf16x8*)&p_lds[wave][1][lm][32 + quad * 8];
            for (int dt = 0; dt < 4; ++dt) {
                int d = dt * 16 + lm;              // d&7 == lm&7
                const bf16* vrow = vbuf + d * 64;
                bf16x8 v0 = *(const bf16x8*)(vrow + ((quad ^ lsw) * 8));
                bf16x8 v1 = *(const bf16x8*)(vrow + (((quad + 4) ^ lsw) * 8));
                oA[dt] = __builtin_amdgcn_mfma_f32_16x16x32_bf16(paA0, v0, oA[dt], 0, 0, 0);
                oA[dt] = __builtin_amdgcn_mfma_f32_16x16x32_bf16(paA1, v1, oA[dt], 0, 0, 0);
                oB[dt] = __builtin_amdgcn_mfma_f32_16x16x32_bf16(paB0, v0, oB[dt], 0, 0, 0);
                oB[dt] = __builtin_amdgcn_mfma_f32_16x16x32_bf16(paB1, v1, oB[dt], 0, 0, 0);
            }
        }
        __syncthreads();   // kv reuse + next-chunk staging drain
    }
#undef STAGE
    float liA = 1.f / lA, liB = 1.f / lB;
    for (int r = 0; r < 4; ++r) {
        float ivA = __shfl(liA, quad * 4 + r);
        float ivB = __shfl(liB, quad * 4 + r);
        int qiA = q0w + quad * 4 + r;
        for (int dt = 0; dt < 4; ++dt) {
            ctx[((size_t)b * SS + qiA) * DD + h * HD + dt * 16 + lm] =
                (bf16)(oA[dt][r] * ivA);
            ctx[((size_t)b * SS + qiA + 16) * DD + h * HD + dt * 16 + lm] =
                (bf16)(oB[dt][r] * ivB);
        }
    }
}

// ---------- host ----------
extern "C" void kernel_launch(void* const* d_in, const int* in_sizes, int n_in,
                              void* d_out, int out_size, void* d_ws, size_t ws_size,
                              hipStream_t stream) {
    const float* hs   = (const float*)d_in[0];
    const float* cosb = (const float*)d_in[1];
    const float* sinb = (const float*)d_in[2];
    const float* Wq = (const float*)d_in[4];
    const float* Wk = (const float*)d_in[5];
    const float* Wv = (const float*)d_in[6];
    const float* Wo = (const float*)d_in[7];
    float* out = (float*)d_out;

    char* ws = (char*)d_ws;
    size_t off = 0;
    auto alloc = [&](size_t bytes) {
        char* p = ws + off;
        off += (bytes + 255) & ~(size_t)255;
        return p;
    };
    const size_t MT = (size_t)BB * SS;                    // 4096 tokens
    bf16* hsb     = (bf16*)alloc(MT * DD * 2);
    bf16* WqkvT   = (bf16*)alloc((size_t)QKVN * DD * 2);
    bf16* WoT     = (bf16*)alloc((size_t)DD * DD * 2);
    bf16* Qr      = (bf16*)alloc(MT * DD * 2);
    bf16* Kr      = (bf16*)alloc(MT * 256 * 2);
    bf16* Vt      = (bf16*)alloc(MT * 256 * 2);
    bf16* ctx     = (bf16*)alloc(MT * DD * 2);

    // 1. prep: tiled weight transposes + hs cast
    prep_kernel<<<384 + 256 + 4096, 256, 0, stream>>>(hs, Wq, Wk, Wv, Wo,
                                                      hsb, WqkvT, WoT);
    // 2. fused QKV projection + RoPE + V scatter (768 blocks = 3/CU)
    gemm_qkv<<<dim3(MT / 128, QKVN / 64), 256, 0, stream>>>(hsb, WqkvT, cosb, sinb,
                                                            Qr, Kr, Vt);
    // 3. attention (512 WGs x 4 waves, 32 q/wave; bid&7 = XCD group)
    attn_kernel<<<512, 256, 0, stream>>>(Qr, Kr, Vt, ctx);
    // 4. output projection (512 blocks = 2/CU, fp32 out)
    gemm_out<<<dim3(MT / 128, DD / 64), 256, 0, stream>>>(ctx, WoT, out,
                                                          (int)MT, DD, DD);

    (void)in_sizes; (void)n_in; (void)out_size; (void)ws_size;
}

// Round 9
// 185.806 us; speedup vs baseline: 1.0976x; 1.0976x over previous
//
#include <hip/hip_runtime.h>

#define BB 2
#define SS 2048
#define DD 1024
#define NH 16
#define NKVH 4
#define HD 64
#define QKVN 1536          // fused Wqkv output columns: 1024 q | 256 k | 256 v
#define SCALE 0.125f       // 64^-0.5, exact power of 2 -> folded into Q frags

typedef __bf16 bf16;
typedef __bf16 bf16x4 __attribute__((ext_vector_type(4)));
typedef __bf16 bf16x8 __attribute__((ext_vector_type(8)));
typedef float floatx4 __attribute__((ext_vector_type(4)));

#define ASYNC16(gp, lp) __builtin_amdgcn_global_load_lds(                      \
    (const __attribute__((address_space(1))) unsigned int*)(gp),               \
    (__attribute__((address_space(3))) unsigned int*)(lp), 16, 0, 0)

// ---------- prep: LDS-tiled weight transposes + hs cast ----------
__global__ __launch_bounds__(256) void prep_kernel(const float* __restrict__ hs,
                                                   const float* __restrict__ Wq,
                                                   const float* __restrict__ Wk,
                                                   const float* __restrict__ Wv,
                                                   const float* __restrict__ Wo,
                                                   bf16* __restrict__ hsb,
                                                   bf16* __restrict__ WqkvT,
                                                   bf16* __restrict__ WoT) {
    __shared__ bf16 tl[64 * 66];
    int bidx = blockIdx.x, t = threadIdx.x;
    const int NT_QKV = 16 * 24;    // K/64 x QKVN/64
    const int NT_WO  = 16 * 16;
    if (bidx < NT_QKV + NT_WO) {
        int k0, n0, stride;
        const float* src;
        bf16* dst;
        if (bidx < NT_QKV) {
            int tk = bidx / 24, tn = bidx - tk * 24;
            k0 = tk * 64; n0 = tn * 64;
            if (n0 < 1024)      { src = Wq + n0;          stride = 1024; }
            else if (n0 < 1280) { src = Wk + (n0 - 1024); stride = 256;  }
            else                { src = Wv + (n0 - 1280); stride = 256;  }
            dst = WqkvT + (size_t)n0 * DD + k0;
        } else {
            int j = bidx - NT_QKV;
            int tk = j >> 4, tn = j & 15;
            k0 = tk * 64; n0 = tn * 64;
            src = Wo + n0; stride = 1024;
            dst = WoT + (size_t)n0 * DD + k0;
        }
        int c = t & 63, r0 = (t >> 6) * 16;
        for (int j = 0; j < 16; ++j)
            tl[c * 66 + r0 + j] = (bf16)src[(size_t)(k0 + r0 + j) * stride + c];
        __syncthreads();
        for (int j = 0; j < 16; ++j)
            dst[(size_t)(r0 + j) * DD + c] = tl[(r0 + j) * 66 + c];
    } else {
        int i = (bidx - (NT_QKV + NT_WO)) * 256 + t;   // n4 = 1048576 exactly
        float4 v = ((const float4*)hs)[i];
        ((bf16x4*)hsb)[i] = bf16x4{(bf16)v.x, (bf16)v.y, (bf16)v.z, (bf16)v.w};
    }
}

// ---------- QKV GEMM (128x64 tile) with fused RoPE + scatter epilogue ----------
__global__ __launch_bounds__(256) void gemm_qkv(const bf16* __restrict__ A,
                                                const bf16* __restrict__ Bt,
                                                const float* __restrict__ cosb,
                                                const float* __restrict__ sinb,
                                                bf16* __restrict__ Qr,
                                                bf16* __restrict__ Kr,
                                                bf16* __restrict__ Vt) {
    __shared__ bf16 As[128 * 32];
    __shared__ bf16 Bs[64 * 32];
    int t = threadIdx.x;
    int wave = t >> 6, lane = t & 63;
    int lm = lane & 15, quad = lane >> 4;
    int m0 = blockIdx.x * 128, n0 = blockIdx.y * 64;
    int wr = wave >> 1, wc = wave & 1;      // 64m x 32n per wave
    const int K = DD;

    int srow = t >> 2;                      // 0..63
    int scol = (t & 3) * 8;
    const bf16* ga = A  + (size_t)(m0 + srow) * K + scol;
    const bf16* gb = Bt + (size_t)(n0 + srow) * K + scol;
    bf16* la0 = &As[wave * 512];
    bf16* lb0 = &Bs[wave * 512];

    floatx4 acc[4][2];
    for (int i = 0; i < 4; ++i)
        for (int j = 0; j < 2; ++j) acc[i][j] = floatx4{0.f, 0.f, 0.f, 0.f};

    for (int ks = 0; ks < K; ks += 32) {
        __syncthreads();
        ASYNC16(ga + ks,                la0);
        ASYNC16(ga + ks + (size_t)64*K, la0 + 2048);
        ASYNC16(gb + ks,                lb0);
        __syncthreads();
        bf16x8 af[4], bfr[2];
        for (int mi = 0; mi < 4; ++mi)
            af[mi] = *(const bf16x8*)&As[(wr * 64 + mi * 16 + lm) * 32 + quad * 8];
        for (int ni = 0; ni < 2; ++ni)
            bfr[ni] = *(const bf16x8*)&Bs[(wc * 32 + ni * 16 + lm) * 32 + quad * 8];
        for (int mi = 0; mi < 4; ++mi)
            for (int ni = 0; ni < 2; ++ni)
                acc[mi][ni] = __builtin_amdgcn_mfma_f32_16x16x32_bf16(af[mi], bfr[ni],
                                                                      acc[mi][ni], 0, 0, 0);
    }
    bool odd = lm & 1;
    for (int mi = 0; mi < 4; ++mi)
        for (int ni = 0; ni < 2; ++ni) {
            int c0 = n0 + wc * 32 + ni * 16;
            int row0 = m0 + wr * 64 + mi * 16 + quad * 4;
            floatx4 a = acc[mi][ni];
            int d = (c0 & 63) + lm;
            if (c0 < 1280) {               // Q or K: apply RoPE
                int ii = d >> 1;
                for (int r = 0; r < 4; ++r) {
                    int row = row0 + r;
                    float self = a[r];
                    float part = __shfl_xor(self, 1);
                    float cc = cosb[(size_t)row * 32 + ii];
                    float sn = sinb[(size_t)row * 32 + ii];
                    float outv = odd ? fmaf(part, sn, self * cc)
                                     : fmaf(self, cc, -part * sn);
                    int s = row & (SS - 1), b = row >> 11;
                    if (c0 < 1024) {
                        int h = c0 >> 6;
                        Qr[((size_t)(b * NH + h) * SS + s) * HD + d] = (bf16)outv;
                    } else {
                        int kvh = (c0 - 1024) >> 6;
                        Kr[((size_t)(b * NKVH + kvh) * SS + s) * HD + d] = (bf16)outv;
                    }
                }
            } else {                       // V: transposed packed store
                int kvh = (c0 - 1280) >> 6;
                bf16x4 pk = {(bf16)a[0], (bf16)a[1], (bf16)a[2], (bf16)a[3]};
                int s0 = row0 & (SS - 1), b = row0 >> 11;
                *(bf16x4*)&Vt[((size_t)(b * NKVH + kvh) * HD + d) * SS + s0] = pk;
            }
        }
}

// ---------- O-projection GEMM (128x64 tile, fp32 out) ----------
__global__ __launch_bounds__(256) void gemm_out(const bf16* __restrict__ A,
                                                const bf16* __restrict__ Bt,
                                                float* __restrict__ Cf,
                                                int M, int N, int K) {
    __shared__ bf16 As[128 * 32];
    __shared__ bf16 Bs[64 * 32];
    int t = threadIdx.x;
    int wave = t >> 6, lane = t & 63;
    int lm = lane & 15, quad = lane >> 4;
    int m0 = blockIdx.x * 128, n0 = blockIdx.y * 64;
    int wr = wave >> 1, wc = wave & 1;

    int srow = t >> 2;
    int scol = (t & 3) * 8;
    const bf16* ga = A  + (size_t)(m0 + srow) * K + scol;
    const bf16* gb = Bt + (size_t)(n0 + srow) * K + scol;
    bf16* la0 = &As[wave * 512];
    bf16* lb0 = &Bs[wave * 512];

    floatx4 acc[4][2];
    for (int i = 0; i < 4; ++i)
        for (int j = 0; j < 2; ++j) acc[i][j] = floatx4{0.f, 0.f, 0.f, 0.f};

    for (int ks = 0; ks < K; ks += 32) {
        __syncthreads();
        ASYNC16(ga + ks,                la0);
        ASYNC16(ga + ks + (size_t)64*K, la0 + 2048);
        ASYNC16(gb + ks,                lb0);
        __syncthreads();
        bf16x8 af[4], bfr[2];
        for (int mi = 0; mi < 4; ++mi)
            af[mi] = *(const bf16x8*)&As[(wr * 64 + mi * 16 + lm) * 32 + quad * 8];
        for (int ni = 0; ni < 2; ++ni)
            bfr[ni] = *(const bf16x8*)&Bs[(wc * 32 + ni * 16 + lm) * 32 + quad * 8];
        for (int mi = 0; mi < 4; ++mi)
            for (int ni = 0; ni < 2; ++ni)
                acc[mi][ni] = __builtin_amdgcn_mfma_f32_16x16x32_bf16(af[mi], bfr[ni],
                                                                      acc[mi][ni], 0, 0, 0);
    }
    for (int mi = 0; mi < 4; ++mi)
        for (int ni = 0; ni < 2; ++ni)
            for (int r = 0; r < 4; ++r) {
                size_t row = (size_t)(m0 + wr * 64 + mi * 16 + quad * 4 + r);
                Cf[row * N + n0 + wc * 32 + ni * 16 + lm] = acc[mi][ni][r];
            }
}

// ---------- flash attention: sequential complementary q-block pairs ----------
// R4's verified pipeline; each WG processes q-block i THEN q-block 31-i:
// (i+1)+(32-i) = 33 chunks per WG, exactly balanced -> no straggler tail.
// 512 WGs x 256 thr (LDS 41984 -> 3/CU cap, 2/CU resident, all co-resident).
// bid&7 = (b,kvh) XCD pin; block B's K/V prefix = block A's scan (L2-warm).
__global__ __launch_bounds__(256, 3) void attn_kernel(const bf16* __restrict__ Qr,
                                                      const bf16* __restrict__ Kr,
                                                      const bf16* __restrict__ Vt,
                                                      bf16* __restrict__ ctx) {
    __shared__ __align__(16) bf16 kv[2][8192];       // per buf: K [0,4096) | V [4096,8192)
    __shared__ __align__(16) bf16 p_lds[4][16][72];
    int t = threadIdx.x;
    int wave = t >> 6, lane = t & 63;
    int lm = lane & 15, quad = lane >> 4;

    int bid = blockIdx.x;
    int grp = bid & 7;                 // XCD group = b*4 + kvh
    int j = bid >> 3;                  // 0..63 within group
    int b = grp >> 2, kvh = grp & 3;
    int h = kvh * 4 + (j & 3);
    int i = j >> 2;                    // pair index 0..15 -> blocks {i, 31-i}

    const bf16* kbase = Kr + (size_t)(b * NKVH + kvh) * SS * HD;
    const bf16* vbase = Vt + (size_t)(b * NKVH + kvh) * HD * SS;
    int srow = t >> 3;                         // 0..31
    int su   = (t & 7) ^ (srow & 7);           // XOR swizzle (async-LDS forbids pads)
    const bf16* gk = kbase + (size_t)srow * HD + su * 8;
    const bf16* gv = vbase + (size_t)srow * SS + su * 8;

#define STAGE(bufi, kb) do { bf16* l = &kv[bufi][0] + wave * 512;              \
        ASYNC16(gk + (size_t)(kb) * HD,        l);                             \
        ASYNC16(gk + (size_t)((kb) + 32) * HD, l + 2048);                      \
        ASYNC16(gv + (kb),                     l + 4096);                      \
        ASYNC16(gv + (size_t)32 * SS + (kb),   l + 6144); } while (0)

    for (int pass = 0; pass < 2; ++pass) {
        int qb = pass ? (31 - i) : i;
        int q0w = qb * 64 + wave * 16;

        // Q fragments, pre-scaled by SCALE (0.125 = 2^-3, exact in bf16)
        const bf16* qp = Qr + ((size_t)(b * NH + h) * SS + q0w + lm) * HD;
        bf16x8 qf0 = *(const bf16x8*)(qp + quad * 8);
        bf16x8 qf1 = *(const bf16x8*)(qp + 32 + quad * 8);
        for (int e = 0; e < 8; ++e) {
            qf0[e] = (bf16)((float)qf0[e] * SCALE);
            qf1[e] = (bf16)((float)qf1[e] * SCALE);
        }

        float m_prev = -1e30f, l_prev = 0.f;
        floatx4 o[4];
        for (int dt = 0; dt < 4; ++dt) o[dt] = floatx4{0.f, 0.f, 0.f, 0.f};

        int nch = qb + 1;
        STAGE(0, 0);
        __syncthreads();                       // buf0 staged (vmcnt drained)

        for (int ck = 0; ck < nch; ++ck) {
            int kb = ck * 64;
            if (ck + 1 < nch) STAGE((ck + 1) & 1, kb + 64);
            const bf16* kbuf = &kv[ck & 1][0];
            const bf16* vbuf = kbuf + 4096;

            // S^T = K·Q^T (rows = keys, cols = queries; lane lm = its query)
            floatx4 st[4];
            for (int tt = 0; tt < 4; ++tt) {
                int kk = tt * 16 + lm;             // kk&7 == lm&7
                const bf16* krow = kbuf + kk * 64;
                bf16x8 k0 = *(const bf16x8*)(krow + ((quad ^ (lm & 7)) * 8));
                bf16x8 k1 = *(const bf16x8*)(krow + (((quad + 4) ^ (lm & 7)) * 8));
                floatx4 s = {0.f, 0.f, 0.f, 0.f};
                s = __builtin_amdgcn_mfma_f32_16x16x32_bf16(k0, qf0, s, 0, 0, 0);
                s = __builtin_amdgcn_mfma_f32_16x16x32_bf16(k1, qf1, s, 0, 0, 0);
                st[tt] = s;
            }
            if (ck == nch - 1) {                   // causal mask (diag chunk only)
                for (int tt = 0; tt < 4; ++tt)
                    for (int r = 0; r < 4; ++r)
                        if (kb + tt * 16 + quad * 4 + r > q0w + lm) st[tt][r] = -1e30f;
            }
            // tree max over 16 regs + 2 quad shuffles
            float tm[4];
            for (int tt = 0; tt < 4; ++tt)
                tm[tt] = fmaxf(fmaxf(st[tt][0], st[tt][1]), fmaxf(st[tt][2], st[tt][3]));
            float mx = fmaxf(fmaxf(tm[0], tm[1]), fmaxf(tm[2], tm[3]));
            mx = fmaxf(mx, __shfl_xor(mx, 16));
            mx = fmaxf(mx, __shfl_xor(mx, 32));
            float m_new = fmaxf(m_prev, mx);
            float alpha = __expf(m_prev - m_new);
            m_prev = m_new;
            float ts[4];
            for (int tt = 0; tt < 4; ++tt) {
                float p0 = __expf(st[tt][0] - m_new);
                float p1 = __expf(st[tt][1] - m_new);
                float p2 = __expf(st[tt][2] - m_new);
                float p3 = __expf(st[tt][3] - m_new);
                st[tt] = floatx4{p0, p1, p2, p3};
                ts[tt] = (p0 + p1) + (p2 + p3);
            }
            float ls = (ts[0] + ts[1]) + (ts[2] + ts[3]);
            ls += __shfl_xor(ls, 16);
            ls += __shfl_xor(ls, 32);
            l_prev = l_prev * alpha + ls;

            // P^T -> A-layout via wave-private LDS (no barrier)
            for (int tt = 0; tt < 4; ++tt) {
                bf16x4 pk = {(bf16)st[tt][0], (bf16)st[tt][1],
                             (bf16)st[tt][2], (bf16)st[tt][3]};
                *(bf16x4*)&p_lds[wave][lm][tt * 16 + quad * 4] = pk;
            }
            for (int r = 0; r < 4; ++r) {
                float a = __shfl(alpha, quad * 4 + r);
                for (int dt = 0; dt < 4; ++dt) o[dt][r] *= a;
            }
            bf16x8 pa0 = *(const bf16x8*)&p_lds[wave][lm][quad * 8];
            bf16x8 pa1 = *(const bf16x8*)&p_lds[wave][lm][32 + quad * 8];
            for (int dt = 0; dt < 4; ++dt) {
                int d = dt * 16 + lm;              // d&7 == lm&7
                const bf16* vrow = vbuf + d * 64;
                bf16x8 v0 = *(const bf16x8*)(vrow + ((quad ^ (lm & 7)) * 8));
                bf16x8 v1 = *(const bf16x8*)(vrow + (((quad + 4) ^ (lm & 7)) * 8));
                o[dt] = __builtin_amdgcn_mfma_f32_16x16x32_bf16(pa0, v0, o[dt], 0, 0, 0);
                o[dt] = __builtin_amdgcn_mfma_f32_16x16x32_bf16(pa1, v1, o[dt], 0, 0, 0);
            }
            __syncthreads();   // kv reuse + next-chunk staging drain
        }
        float linv = 1.f / l_prev;
        for (int r = 0; r < 4; ++r) {
            float inv = __shfl(linv, quad * 4 + r);
            int qi = q0w + quad * 4 + r;
            for (int dt = 0; dt < 4; ++dt)
                ctx[((size_t)b * SS + qi) * DD + h * HD + dt * 16 + lm] =
                    (bf16)(o[dt][r] * inv);
        }
    }
#undef STAGE
}

// ---------- host ----------
extern "C" void kernel_launch(void* const* d_in, const int* in_sizes, int n_in,
                              void* d_out, int out_size, void* d_ws, size_t ws_size,
                              hipStream_t stream) {
    const float* hs   = (const float*)d_in[0];
    const float* cosb = (const float*)d_in[1];
    const float* sinb = (const float*)d_in[2];
    const float* Wq = (const float*)d_in[4];
    const float* Wk = (const float*)d_in[5];
    const float* Wv = (const float*)d_in[6];
    const float* Wo = (const float*)d_in[7];
    float* out = (float*)d_out;

    char* ws = (char*)d_ws;
    size_t off = 0;
    auto alloc = [&](size_t bytes) {
        char* p = ws + off;
        off += (bytes + 255) & ~(size_t)255;
        return p;
    };
    const size_t MT = (size_t)BB * SS;                    // 4096 tokens
    bf16* hsb     = (bf16*)alloc(MT * DD * 2);
    bf16* WqkvT   = (bf16*)alloc((size_t)QKVN * DD * 2);
    bf16* WoT     = (bf16*)alloc((size_t)DD * DD * 2);
    bf16* Qr      = (bf16*)alloc(MT * DD * 2);
    bf16* Kr      = (bf16*)alloc(MT * 256 * 2);
    bf16* Vt      = (bf16*)alloc(MT * 256 * 2);
    bf16* ctx     = (bf16*)alloc(MT * DD * 2);

    // 1. prep: tiled weight transposes + hs cast
    prep_kernel<<<384 + 256 + 4096, 256, 0, stream>>>(hs, Wq, Wk, Wv, Wo,
                                                      hsb, WqkvT, WoT);
    // 2. fused QKV projection + RoPE + V scatter (768 blocks = 3/CU)
    gemm_qkv<<<dim3(MT / 128, QKVN / 64), 256, 0, stream>>>(hsb, WqkvT, cosb, sinb,
                                                            Qr, Kr, Vt);
    // 3. attention (512 WGs: bid&7 = XCD group; sequential paired q-blocks, 33 chunks/WG)
    attn_kernel<<<512, 256, 0, stream>>>(Qr, Kr, Vt, ctx);
    // 4. output projection (512 blocks = 2/CU, fp32 out)
    gemm_out<<<dim3(MT / 128, DD / 64), 256, 0, stream>>>(ctx, WoT, out,
                                                          (int)MT, DD, DD);

    (void)in_sizes; (void)n_in; (void)out_size; (void)ws_size;
}